// Round 8
// baseline (265.703 us; speedup 1.0000x reference)
//
#include <hip/hip_runtime.h>
#include <math.h>

#define BB    32
#define TT    1024
#define VV    1024
#define LM    128
#define SS    257        // 2*LM+1 extended states
#define SP    272        // floats per row = 1088 B = 17 full cache lines
#define RNORM 4          // per-lane renorm cadence (growth <= 2^55 per interval)
#define PF    16         // DP prefetch ring depth (STATIC indices -> registers)
#define RPW   8          // rows per wave in the row kernel

// ---------------------------------------------------------------------------
// Kernel A: one wave per 8 CONTIGUOUS rows, register double-buffered; fused
// online-softmax butterfly.  BLANK-CENTERED output: stores per lane the label
// RATIOS r = exp(x_label - x_blank) as float2 (blank prob == 1 by
// construction), plus slot 256 = LSE - x_blank.  Block 0 zeroes out.
// (unchanged from round 5, which passed with absmax 0)
// ---------------------------------------------------------------------------
__global__ __launch_bounds__(256) void ctc_row_kernel(
    const float* __restrict__ ys_hat, const int* __restrict__ ys_pad,
    const int* __restrict__ hlens, float* __restrict__ lp,
    float* __restrict__ out)
{
    __shared__ float srow[4][VV];
    if (blockIdx.x == 0 && threadIdx.x == 0) *out = 0.f;  // before dp runs
    const int w    = threadIdx.x >> 6;
    const int lane = threadIdx.x & 63;
    const int gw   = blockIdx.x * 4 + w;      // 0..4095 global wave id
    const int b    = gw >> 7;                 // 128 waves per batch
    const int t0   = (gw & 127) * RPW;        // first frame of this wave
    const int hl   = hlens[b];
    int nrows = hl - t0;
    if (nrows <= 0) return;                   // wave-uniform exit
    if (nrows > RPW) nrows = RPW;

    const int lab0 = ys_pad[b * LM + 2 * lane];      // label for state 4l+1
    const int lab1 = ys_pad[b * LM + 2 * lane + 1];  // label for state 4l+3
    const float* xr  = ys_hat + ((size_t)b * TT + t0) * VV;
    float*       lpo = lp     + ((size_t)b * TT + t0) * SP;

    float4 va0, va1, va2, va3, vb0, vb1, vb2, vb3;
    {
        const float4* cx = (const float4*)xr;
        va0 = cx[lane]; va1 = cx[lane + 64]; va2 = cx[lane + 128]; va3 = cx[lane + 192];
    }

#define ROW_STEP(C0, C1, C2, C3, N0, N1, N2, N3)                               \
    {                                                                          \
        if (i + 1 < nrows) {  /* prefetch next row while we reduce this one */ \
            const float4* nx = (const float4*)(xr + (size_t)(i + 1) * VV);     \
            N0 = nx[lane]; N1 = nx[lane + 64];                                 \
            N2 = nx[lane + 128]; N3 = nx[lane + 192];                          \
        }                                                                      \
        float4* sw = (float4*)srow[w];                                         \
        sw[lane] = C0; sw[lane + 64] = C1;                                     \
        sw[lane + 128] = C2; sw[lane + 192] = C3;                              \
        float m = fmaxf(fmaxf(fmaxf(C0.x, C0.y), fmaxf(C0.z, C0.w)),          \
                        fmaxf(fmaxf(C1.x, C1.y), fmaxf(C1.z, C1.w)));          \
        m = fmaxf(m, fmaxf(fmaxf(fmaxf(C2.x, C2.y), fmaxf(C2.z, C2.w)),       \
                           fmaxf(fmaxf(C3.x, C3.y), fmaxf(C3.z, C3.w))));      \
        float s = __expf(C0.x - m) + __expf(C0.y - m) + __expf(C0.z - m) +     \
                  __expf(C0.w - m) + __expf(C1.x - m) + __expf(C1.y - m) +     \
                  __expf(C1.z - m) + __expf(C1.w - m) + __expf(C2.x - m) +     \
                  __expf(C2.y - m) + __expf(C2.z - m) + __expf(C2.w - m) +     \
                  __expf(C3.x - m) + __expf(C3.y - m) + __expf(C3.z - m) +     \
                  __expf(C3.w - m);                                            \
        _Pragma("unroll")                                                      \
        for (int off = 32; off; off >>= 1) {  /* fused max+sum butterfly */    \
            const float mo = __shfl_xor(m, off);                               \
            const float so = __shfl_xor(s, off);                               \
            const float mn = fmaxf(m, mo);                                     \
            s = s * __expf(m - mn) + so * __expf(mo - mn);                     \
            m = mn;                                                            \
        }                                                                      \
        const float xbv = srow[w][0];                                          \
        const float x1v = srow[w][lab0];                                       \
        const float x3v = srow[w][lab1];                                       \
        ((float2*)(lpo + (size_t)i * SP))[lane] =                              \
            make_float2(__expf(x1v - xbv), __expf(x3v - xbv));                 \
        if (lane < 16) {  /* slots 256..271 = one full 64B line */             \
            float val = 0.f;                                                   \
            if (lane == 0) val = __logf(s) + (m - xbv);  /* LSE - x_blank */   \
            lpo[(size_t)i * SP + 256 + lane] = val;                            \
        }                                                                      \
    }

    int i = 0;
    for (;;) {
        ROW_STEP(va0, va1, va2, va3, vb0, vb1, vb2, vb3)
        if (++i >= nrows) break;
        ROW_STEP(vb0, vb1, vb2, vb3, va0, va1, va2, va3)
        if (++i >= nrows) break;
    }
#undef ROW_STEP
}

// ---------------------------------------------------------------------------
// DPP helpers.  row_shr reduce (ssw): result in lane 15 of each 16-lane row.
// ---------------------------------------------------------------------------
#define DPP_ADDF(x, ctrl)                                                       \
    x = x + __int_as_float(__builtin_amdgcn_update_dpp(                         \
            0, __float_as_int(x), ctrl, 0xf, 0xf, true))
#define RLANEF(x, l) __int_as_float(__builtin_amdgcn_readlane(__float_as_int(x), (l)))

// Full-wave shift-down-by-1 (lane l gets lane l-1; lane 0 gets 0) as a single
// pure-VALU op: DPP wave_shr:1 (ctrl 0x138), bound_ctrl=1 zero-fills lane 0.
__device__ __forceinline__ float dpp_shr1_f32(float x)
{
    return __int_as_float(__builtin_amdgcn_update_dpp(
        0, __float_as_int(x), 0x138, 0xf, 0xf, true));
}
__device__ __forceinline__ int dpp_shr1_i32(int x)
{
    return __builtin_amdgcn_update_dpp(0, x, 0x138, 0xf, 0xf, true);
}

// ---------------------------------------------------------------------------
// Kernel B: ONE WAVE PER BATCH, beta in F32 with PER-LANE block-float scale:
// true_state = a_i * 2^kl (kl int per lane).  Round-7's wave-uniform f32
// failed (terminal underflowed vs the wave max -> log(0) = inf).  Per-lane
// scales fix the range STRUCTURALLY:
//  * within-lane spread bounded: c1>=a0*ry, c2>=a1, c3>=a2*rw, c4>=a3 each
//    frame => in-lane states stay within ~e^40 ~ 2^58 of the lane max.
//  * adjacent-lane scale gap bounded: lane l+1 max >= lane l's a3 (1-frame
//    lag) => |k_{l-1}-k_l| <= ~60 bits << 127-bit correction window.
//  * cross-lane term: n1 = dpp(a3) * 2^(k_left - k) (exact exponent-built
//    factor, clamped to [-127,127] -> 0.0 when neighbor negligible).
//  * dormant lanes (wavefront not arrived) ADOPT k_left at their wake frame
//    (live flag) -- else a frozen k could sit >127 bits off and the clamp
//    would kill the incoming mass.
//  * renorm every 4 frames is PER-LANE ONLY (15 VALU ops, no DPP-max chain,
//    no readlane): e = exponent(max of 5 states); scale by exact 2^-e;
//    kl += e.  Dormant lanes get e=-126 on zeros -- harmless, kl is
//    overwritten at wake.
// Final: per-lane kl exported; lane 0 combines terminal states in f64.
// ---------------------------------------------------------------------------
__global__ __launch_bounds__(64, 1) void ctc_dp_kernel(
    const float* __restrict__ lp_all, const int* __restrict__ ys_pad,
    const int* __restrict__ hlens, const int* __restrict__ ys_lens,
    float* __restrict__ out)
{
    __shared__ float sh[SS];
    __shared__ int   shk[64];
    const int b    = blockIdx.x;
    const int lane = threadIdx.x;
    const int hl   = hlens[b];
    const float* lp = lp_all + (size_t)b * TT * SP;

    // ---- ss: sum of (LSE_t - x_blank,t) over t < hl, batched loads ----
    float sv[16];
#pragma unroll
    for (int jj = 0; jj < 16; ++jj)
        sv[jj] = lp[(size_t)(lane + jj * 64) * SP + 256];

    // ring prime overlaps the ss loads (hl >= 512 guarantees rows 1..PF)
    float2 qr[PF];
#pragma unroll
    for (int j = 0; j < PF; ++j)
        qr[j] = ((const float2*)(lp + (size_t)(1 + j) * SP))[lane];

    const int* lab = ys_pad + b * LM;
    const float sk1f = (lane > 0 && lab[2 * lane] != lab[2 * lane - 1]) ? 1.0f : 0.0f;
    const float sk3f = (lab[2 * lane + 1] != lab[2 * lane]) ? 1.0f : 0.0f;

    float ssv = 0.f;
#pragma unroll
    for (int jj = 0; jj < 16; ++jj)
        ssv += (lane + jj * 64 < hl) ? sv[jj] : 0.f;
    DPP_ADDF(ssv, 0x111); DPP_ADDF(ssv, 0x112); DPP_ADDF(ssv, 0x114); DPP_ADDF(ssv, 0x118);
    const float ssw = RLANEF(ssv, 15) + RLANEF(ssv, 31) + RLANEF(ssv, 47) + RLANEF(ssv, 63);

    // t = 0 init in beta-units: b0 = 1, b1 = ry(0) (both lane 0)
    const float2 q0 = ((const float2*)lp)[lane];
    float a0 = (lane == 0) ? 1.0f : 0.0f;
    float a1 = (lane == 0) ? q0.x : 0.0f;
    float a2 = 0.0f, a3 = 0.0f, a4 = 0.0f;
    int   kl = 0;
    bool  live = (lane == 0);

#define RENORM_BODY                                                            \
    {                                                                          \
        float m = fmaxf(fmaxf(fmaxf(a0, a1), fmaxf(a2, a3)), a4);              \
        const int e = (__float_as_int(m) >> 23) - 126;  /* m in [.5,1)->0 */   \
        const float sc = __int_as_float((127 - e) << 23);  /* exact 2^-e */    \
        kl += e;                     /* dormant: m=0 -> e=-126, harmless */    \
        a0 *= sc; a1 *= sc; a2 *= sc; a3 *= sc; a4 *= sc;                      \
    }

#define DP_STEP(q)                                                             \
    {                                                                          \
        const float ry = (q).x;            /* exp(x_lab0 - x_blank) */         \
        const float rw = (q).y;            /* exp(x_lab1 - x_blank) */         \
        const float n1r = dpp_shr1_f32(a3);   /* left a3, LEFT scale */        \
        const int   kp  = dpp_shr1_i32(kl);   /* left lane's k */              \
        int d = kp - kl;                                                       \
        d = d < -127 ? -127 : (d > 127 ? 127 : d);                             \
        float ds = __int_as_float((127 + d) << 23);  /* 2^d; d=-127 -> 0.0 */  \
        const bool wk = (!live) && (n1r > 0.0f);     /* wake: adopt scale */   \
        kl = wk ? kp : kl;                                                     \
        ds = wk ? 1.0f : ds;                                                   \
        live = live || wk;                                                     \
        const float n1 = n1r * ds;         /* left a3 in MY scale */           \
        const float c0 = a0 + n1;                        /* blank: no mul */   \
        const float c1 = fmaf(sk1f, n1, a0 + a1) * ry;                         \
        const float c2 = a2 + a1;                        /* blank: no mul */   \
        const float c3 = (a3 + fmaf(sk3f, a1, a2)) * rw;                       \
        const float c4 = a4 + a3;          /* state 256 (blank); lane63 */     \
        a0 = c0; a1 = c1; a2 = c2; a3 = c3; a4 = c4;                           \
    }

    int t0 = 1;
    // main loop: stride PF=16, all frames < hl, all prefetches <= hl-1,
    // renorm AFTER the step at static positions (j&3)==3 -> every 4 frames,
    // phase-aligned with the tail's (t&3)==0 check (t=t0+j, t0=1+16n).
    for (; t0 + 2 * PF - 1 <= hl - 1; t0 += PF) {
        const float* pfp = lp + (size_t)(t0 + PF) * SP;
#pragma unroll
        for (int j = 0; j < PF; ++j) {          // j static -> ring in VGPRs
            const float2 q = qr[j];
            qr[j] = ((const float2*)(pfp + (size_t)j * SP))[lane];
            DP_STEP(q)
            if ((j & 3) == 3) RENORM_BODY
        }
    }
    // tail: 16..31 frames, clamped prefetch, per-frame guards
    for (; t0 < hl; t0 += PF) {
#pragma unroll
        for (int j = 0; j < PF; ++j) {
            const int t = t0 + j;
            const float2 q = qr[j];
            int tp = t + PF; if (tp > hl - 1) tp = hl - 1;
            qr[j] = ((const float2*)(lp + (size_t)tp * SP))[lane];
            if (t < hl) {                        // wave-uniform
                DP_STEP(q)
                if ((t & (RNORM - 1)) == 0) RENORM_BODY
            }
        }
    }
#undef DP_STEP
#undef RENORM_BODY

    sh[4 * lane]     = a0;
    sh[4 * lane + 1] = a1;
    sh[4 * lane + 2] = a2;
    sh[4 * lane + 3] = a3;
    shk[lane]        = kl;
    if (lane == 63) sh[256] = a4;    // state 256 shares lane 63's kl
    __syncthreads();                             // single wave
    if (lane == 0) {
        const int L  = ys_lens[b];
        const int s1 = 2 * L, s2 = 2 * L - 1;
        const float v1 = sh[s1], v2 = sh[s2];
        const int l1 = (s1 >> 2) > 63 ? 63 : (s1 >> 2);
        const int k1 = shk[l1], k2 = shk[s2 >> 2];
        const int km = (k1 > k2) ? k1 : k2;
        int d1 = 127 + (k1 - km); if (d1 < 0) d1 = 0;   // 2^(k-km), clamped
        int d2 = 127 + (k2 - km); if (d2 < 0) d2 = 0;
        const double w1 = (double)v1 * (double)__int_as_float(d1 << 23);
        const double w2 = (double)v2 * (double)__int_as_float(d2 << 23);
        const double loss = (double)ssw -
            (log(w1 + w2) + (double)km * 0.6931471805599453);
        atomicAdd(out, (float)(loss * (1.0 / (double)BB)));
    }
}

extern "C" void kernel_launch(void* const* d_in, const int* in_sizes, int n_in,
                              void* d_out, int out_size, void* d_ws, size_t ws_size,
                              hipStream_t stream) {
    const float* ys_hat  = (const float*)d_in[0];
    const int*   ys_pad  = (const int*)d_in[1];
    const int*   hlens   = (const int*)d_in[2];
    const int*   ys_lens = (const int*)d_in[3];
    float* out = (float*)d_out;

    float* lp_raw = (float*)d_ws;        // [B, T, SP] floats (~35.7 MB)

    // out is zeroed by ctc_row_kernel block 0 (stream-ordered before dp).
    ctc_row_kernel<<<BB * TT / (4 * RPW), 256, 0, stream>>>(ys_hat, ys_pad, hlens, lp_raw, out);
    ctc_dp_kernel<<<BB, 64, 0, stream>>>(lp_raw, ys_pad, hlens, ys_lens, out);
}

// Round 10
// 228.401 us; speedup vs baseline: 1.1633x; 1.1633x over previous
//
#include <hip/hip_runtime.h>
#include <math.h>

#define BB    32
#define TT    1024
#define VV    1024
#define LM    128
#define SS    257        // 2*LM+1 extended states
#define SP    272        // floats per row = 1088 B = 17 full cache lines
#define RNORM 16         // renormalize every 16 DP steps (f64: huge margin)
#define PF    16         // DP prefetch ring depth (STATIC indices -> registers)
#define RPW   8          // rows per wave in the row kernel

// ---------------------------------------------------------------------------
// Kernel A (r5, passed absmax 0): one wave per 8 CONTIGUOUS rows, register
// double-buffered; fused online-softmax butterfly.  BLANK-CENTERED output:
// float2 ratios r = exp(x_label - x_blank) + slot 256 = LSE - x_blank.
// Block 0 zeroes out.
// ---------------------------------------------------------------------------
__global__ __launch_bounds__(256) void ctc_row_kernel(
    const float* __restrict__ ys_hat, const int* __restrict__ ys_pad,
    const int* __restrict__ hlens, float* __restrict__ lp,
    float* __restrict__ out)
{
    __shared__ float srow[4][VV];
    if (blockIdx.x == 0 && threadIdx.x == 0) *out = 0.f;  // before dp runs
    const int w    = threadIdx.x >> 6;
    const int lane = threadIdx.x & 63;
    const int gw   = blockIdx.x * 4 + w;      // 0..4095 global wave id
    const int b    = gw >> 7;                 // 128 waves per batch
    const int t0   = (gw & 127) * RPW;        // first frame of this wave
    const int hl   = hlens[b];
    int nrows = hl - t0;
    if (nrows <= 0) return;                   // wave-uniform exit
    if (nrows > RPW) nrows = RPW;

    const int lab0 = ys_pad[b * LM + 2 * lane];      // label for state 4l+1
    const int lab1 = ys_pad[b * LM + 2 * lane + 1];  // label for state 4l+3
    const float* xr  = ys_hat + ((size_t)b * TT + t0) * VV;
    float*       lpo = lp     + ((size_t)b * TT + t0) * SP;

    float4 va0, va1, va2, va3, vb0, vb1, vb2, vb3;
    {
        const float4* cx = (const float4*)xr;
        va0 = cx[lane]; va1 = cx[lane + 64]; va2 = cx[lane + 128]; va3 = cx[lane + 192];
    }

#define ROW_STEP(C0, C1, C2, C3, N0, N1, N2, N3)                               \
    {                                                                          \
        if (i + 1 < nrows) {  /* prefetch next row while we reduce this one */ \
            const float4* nx = (const float4*)(xr + (size_t)(i + 1) * VV);     \
            N0 = nx[lane]; N1 = nx[lane + 64];                                 \
            N2 = nx[lane + 128]; N3 = nx[lane + 192];                          \
        }                                                                      \
        float4* sw = (float4*)srow[w];                                         \
        sw[lane] = C0; sw[lane + 64] = C1;                                     \
        sw[lane + 128] = C2; sw[lane + 192] = C3;                              \
        float m = fmaxf(fmaxf(fmaxf(C0.x, C0.y), fmaxf(C0.z, C0.w)),          \
                        fmaxf(fmaxf(C1.x, C1.y), fmaxf(C1.z, C1.w)));          \
        m = fmaxf(m, fmaxf(fmaxf(fmaxf(C2.x, C2.y), fmaxf(C2.z, C2.w)),       \
                           fmaxf(fmaxf(C3.x, C3.y), fmaxf(C3.z, C3.w))));      \
        float s = __expf(C0.x - m) + __expf(C0.y - m) + __expf(C0.z - m) +     \
                  __expf(C0.w - m) + __expf(C1.x - m) + __expf(C1.y - m) +     \
                  __expf(C1.z - m) + __expf(C1.w - m) + __expf(C2.x - m) +     \
                  __expf(C2.y - m) + __expf(C2.z - m) + __expf(C2.w - m) +     \
                  __expf(C3.x - m) + __expf(C3.y - m) + __expf(C3.z - m) +     \
                  __expf(C3.w - m);                                            \
        _Pragma("unroll")                                                      \
        for (int off = 32; off; off >>= 1) {  /* fused max+sum butterfly */    \
            const float mo = __shfl_xor(m, off);                               \
            const float so = __shfl_xor(s, off);                               \
            const float mn = fmaxf(m, mo);                                     \
            s = s * __expf(m - mn) + so * __expf(mo - mn);                     \
            m = mn;                                                            \
        }                                                                      \
        const float xbv = srow[w][0];                                          \
        const float x1v = srow[w][lab0];                                       \
        const float x3v = srow[w][lab1];                                       \
        ((float2*)(lpo + (size_t)i * SP))[lane] =                              \
            make_float2(__expf(x1v - xbv), __expf(x3v - xbv));                 \
        if (lane < 16) {  /* slots 256..271 = one full 64B line */             \
            float val = 0.f;                                                   \
            if (lane == 0) val = __logf(s) + (m - xbv);  /* LSE - x_blank */   \
            lpo[(size_t)i * SP + 256 + lane] = val;                            \
        }                                                                      \
    }

    int i = 0;
    for (;;) {
        ROW_STEP(va0, va1, va2, va3, vb0, vb1, vb2, vb3)
        if (++i >= nrows) break;
        ROW_STEP(vb0, vb1, vb2, vb3, va0, va1, va2, va3)
        if (++i >= nrows) break;
    }
#undef ROW_STEP
}

// ---------------------------------------------------------------------------
// DPP helpers.
// ---------------------------------------------------------------------------
#define DPP_ADDF(x, ctrl)                                                       \
    x = x + __int_as_float(__builtin_amdgcn_update_dpp(                         \
            0, __float_as_int(x), ctrl, 0xf, 0xf, true))
#define DPP_IMAX(x, ctrl)                                                       \
    {                                                                           \
        const int _o = __builtin_amdgcn_update_dpp(0, x, ctrl, 0xf, 0xf, true); \
        x = (x > _o) ? x : _o;                                                  \
    }
#define RLANEF(x, l) __int_as_float(__builtin_amdgcn_readlane(__float_as_int(x), (l)))
#define RLANEI(x, l) __builtin_amdgcn_readlane((x), (l))

// lane l gets lane l-1 (lane 0 -> 0): DPP wave_shr:1 (0x138), bound_ctrl=1.
__device__ __forceinline__ double dpp_wave_shr1_f64(double x)
{
    const int lo = __builtin_amdgcn_update_dpp(
        0, __double2loint(x), 0x138, 0xf, 0xf, true);
    const int hi = __builtin_amdgcn_update_dpp(
        0, __double2hiint(x), 0x138, 0xf, 0xf, true);
    return __hiloint2double(hi, lo);
}
// lane l gets lane l+1 (lane 63 -> 0): DPP wave_shl:1 (0x130), bound_ctrl=1.
__device__ __forceinline__ double dpp_wave_shl1_f64(double x)
{
    const int lo = __builtin_amdgcn_update_dpp(
        0, __double2loint(x), 0x130, 0xf, 0xf, true);
    const int hi = __builtin_amdgcn_update_dpp(
        0, __double2hiint(x), 0x130, 0xf, 0xf, true);
    return __hiloint2double(hi, lo);
}

// ---------------------------------------------------------------------------
// Kernel B: TWO WAVES PER BATCH (128 threads/block), f64 state, 4 states/lane
// + state 256 on lane 63.  Bidirectional split at mid = hl/2:
//   wave 0: ss prologue + FORWARD alpha over t = 1..mid-1   (r5 code, bounds
//           swapped hl -> mid; alpha stays in registers)
//   wave 1: BACKWARD beta over t = hl-2..mid, init at terminal states
//           {2L, 2L-1} at t = hl-1; cross-lane via DPP wave_shl:1; beta_mid
//           exported through LDS.
//   combine (wave 0): p = sum_s alpha_{mid-1}(s) * gamma(s),
//           gamma(s) = sum_{s' in succ(s)} beta_mid(s'), succ per CTC graph;
//           loss = ss - (log p + (kf+kb)*ln2).
// Rationale: rounds 4/5/8 showed the frame is f64-latency-bound and op-
// shaving is exhausted; halving the SERIAL DEPTH is the remaining lever.
// Renorm: per-wave, every 16 frames, exact 2^-k + integer ksum (unchanged).
// ---------------------------------------------------------------------------
__global__ __launch_bounds__(128, 1) void ctc_dp_kernel(
    const float* __restrict__ lp_all, const int* __restrict__ ys_pad,
    const int* __restrict__ hlens, const int* __restrict__ ys_lens,
    float* __restrict__ out)
{
    __shared__ double shb[SS + 1];   // beta_mid; shb[257] = 0 pad
    __shared__ int    shk[2];        // ksum fwd / bwd
    const int wid  = threadIdx.x >> 6;
    const int lane = threadIdx.x & 63;
    const int b    = blockIdx.x;
    const int hl   = hlens[b];
    const int mid  = hl >> 1;        // fwd: t<mid; bwd: t>=mid (hl>=512)
    const float* lp = lp_all + (size_t)b * TT * SP;
    const int*  lab = ys_pad + b * LM;

    // transition flags (used by fwd, bwd AND combine; all wave-local)
    const double sk1d = (lane > 0 && lab[2 * lane] != lab[2 * lane - 1]) ? 1.0 : 0.0;
    const double sk3d = (lab[2 * lane + 1] != lab[2 * lane]) ? 1.0 : 0.0;
    // edge 4l+3 -> 4l+5 (right lane's state 1); lane 63 has no such edge.
    const double skBd = (lane < 63 && lab[2 * lane + 2] != lab[2 * lane + 1]) ? 1.0 : 0.0;

    double a0 = 0.0, a1 = 0.0, a2 = 0.0, a3 = 0.0, a4 = 0.0;
    int ksum = 0;
    float ssw = 0.f;
    float2 qr[PF];

#define RENORM_BODY                                                            \
    {                                                                          \
        double m = fmax(fmax(fmax(a0, a1), fmax(a2, a3)), a4);                 \
        m = fmax(m, 1e-300);         /* denormal/zero guard */                 \
        int hi = __double2hiint(m);  /* sign=0: int cmp == mag cmp */          \
        DPP_IMAX(hi, 0x111); DPP_IMAX(hi, 0x112);                              \
        DPP_IMAX(hi, 0x114); DPP_IMAX(hi, 0x118);                              \
        const int h0 = RLANEI(hi, 15), h1 = RLANEI(hi, 31);                    \
        const int h2 = RLANEI(hi, 47), h3 = RLANEI(hi, 63);                    \
        int hw = (h0 > h1) ? h0 : h1;                                          \
        hw = (hw > h2) ? hw : h2;                                              \
        hw = (hw > h3) ? hw : h3;                                              \
        const int k = (hw >> 20) - 1022;            /* m = f*2^k, f in [.5,1) */ \
        const double sc = __hiloint2double((1023 - k) << 20, 0); /* 2^-k */    \
        ksum += k;                                                             \
        a0 *= sc; a1 *= sc; a2 *= sc; a3 *= sc; a4 *= sc;                      \
    }

#define FWD_STEP(q)                                                            \
    {                                                                          \
        const double ry = (double)(q).x;                                       \
        const double rw = (double)(q).y;                                       \
        const double n1 = dpp_wave_shr1_f64(a3);  /* left a3, lane0 -> 0 */    \
        const double c0 = a0 + n1;                                             \
        const double c1 = fma(sk1d, n1, a0 + a1) * ry;                         \
        const double c2 = a2 + a1;                                             \
        const double c3 = (a3 + fma(sk3d, a1, a2)) * rw;                       \
        const double c4 = a4 + a3;         /* state 256; lane63 meaningful */  \
        a0 = c0; a1 = c1; a2 = c2; a3 = c3; a4 = c4;                           \
    }

#define BWD_STEP(q)                                                            \
    {                                                                          \
        const double r0  = (double)(q).x;  /* emission of state 4l+1 */        \
        const double r1  = (double)(q).y;  /* emission of state 4l+3 */        \
        const double n0  = dpp_wave_shl1_f64(a0);  /* right b0, lane63 -> 0 */ \
        const double n1b = dpp_wave_shl1_f64(a1);  /* right b1, lane63 -> 0 */ \
        const double x   = (lane == 63) ? a4 : n0; /* succ(255) = 256 */       \
        const double c0 = a0 + a1;                 /* succ(4l)={4l,4l+1} */    \
        const double c1 = fma(sk3d, a3, a1 + a2) * r0;                         \
        const double c2 = a2 + a3;                                             \
        const double c3 = (a3 + fma(skBd, n1b, x)) * r1;                       \
        a0 = c0; a1 = c1; a2 = c2; a3 = c3;  /* a4: succ(256)={256}, e=1 */    \
    }

    if (wid == 0) {
        // ---- ss: sum of (LSE_t - x_blank,t) over t < hl, batched ----
        float sv[16];
#pragma unroll
        for (int jj = 0; jj < 16; ++jj)
            sv[jj] = lp[(size_t)(lane + jj * 64) * SP + 256];
#pragma unroll
        for (int j = 0; j < PF; ++j)   // ring prime rows 1..PF (overlaps ss)
            qr[j] = ((const float2*)(lp + (size_t)(1 + j) * SP))[lane];
        float ssv = 0.f;
#pragma unroll
        for (int jj = 0; jj < 16; ++jj)
            ssv += (lane + jj * 64 < hl) ? sv[jj] : 0.f;
        DPP_ADDF(ssv, 0x111); DPP_ADDF(ssv, 0x112);
        DPP_ADDF(ssv, 0x114); DPP_ADDF(ssv, 0x118);
        ssw = RLANEF(ssv, 15) + RLANEF(ssv, 31) + RLANEF(ssv, 47) + RLANEF(ssv, 63);

        // t=0 init (beta-units): states 0,1 live in lane 0
        const float2 q0 = ((const float2*)lp)[lane];
        a0 = (lane == 0) ? 1.0 : 0.0;
        a1 = (lane == 0) ? (double)q0.x : 0.0;

        int t0 = 1;
        for (; t0 + 2 * PF - 1 <= mid - 1; t0 += PF) {
            const float* pfp = lp + (size_t)(t0 + PF) * SP;
#pragma unroll
            for (int j = 0; j < PF; ++j) {
                const float2 q = qr[j];
                qr[j] = ((const float2*)(pfp + (size_t)j * SP))[lane];
                if (j == PF - 1) RENORM_BODY
                FWD_STEP(q)
            }
        }
        for (; t0 < mid; t0 += PF) {
#pragma unroll
            for (int j = 0; j < PF; ++j) {
                const int t = t0 + j;
                const float2 q = qr[j];
                int tp = t + PF; if (tp > hl - 1) tp = hl - 1;  // rows < hl valid
                qr[j] = ((const float2*)(lp + (size_t)tp * SP))[lane];
                if (t < mid) {
                    if ((t & (RNORM - 1)) == 0) RENORM_BODY
                    FWD_STEP(q)
                }
            }
        }
        // alpha_{mid-1} stays in registers for the combine
    } else {
        // ---- backward init at t = hl-1: terminal states 2L, 2L-1 ----
        const int L  = ys_lens[b];
        const int sA = 2 * L;        // terminal blank (even, 2..256)
        const int sB = 2 * L - 1;    // terminal label (odd)
        const float2 qe = ((const float2*)(lp + (size_t)(hl - 1) * SP))[lane];
        a0 = (4 * lane     == sA) ? 1.0 : 0.0;
        a2 = (4 * lane + 2 == sA) ? 1.0 : 0.0;
        a1 = (4 * lane + 1 == sB) ? (double)qe.x : 0.0;
        a3 = (4 * lane + 3 == sB) ? (double)qe.y : 0.0;
        a4 = (sA == 256 && lane == 63) ? 1.0 : 0.0;

#pragma unroll
        for (int j = 0; j < PF; ++j)   // ring prime rows hl-2 .. hl-1-PF
            qr[j] = ((const float2*)(lp + (size_t)(hl - 2 - j) * SP))[lane];

        int tt = hl - 2;
        for (; tt - (2 * PF - 1) >= mid; tt -= PF) {
#pragma unroll
            for (int j = 0; j < PF; ++j) {
                const float2 q = qr[j];
                qr[j] = ((const float2*)(lp + (size_t)(tt - PF - j) * SP))[lane];
                if (j == PF - 1) RENORM_BODY
                BWD_STEP(q)
            }
        }
        for (; tt >= mid; tt -= PF) {
#pragma unroll
            for (int j = 0; j < PF; ++j) {
                const int t = tt - j;
                const float2 q = qr[j];
                int tq = tt - PF - j; if (tq < 0) tq = 0;   // rows >= 0 valid
                qr[j] = ((const float2*)(lp + (size_t)tq * SP))[lane];
                if (t >= mid) {
                    if ((t & (RNORM - 1)) == 0) RENORM_BODY
                    BWD_STEP(q)
                }
            }
        }
        // export beta_mid
        shb[4 * lane]     = a0;
        shb[4 * lane + 1] = a1;
        shb[4 * lane + 2] = a2;
        shb[4 * lane + 3] = a3;
        if (lane == 63) { shb[256] = a4; shb[257] = 0.0; }
    }
#undef FWD_STEP
#undef BWD_STEP
#undef RENORM_BODY

    if (lane == 0) shk[wid] = ksum;
    __syncthreads();

    if (wid == 0) {
        // gamma(s) = sum over successors of s of beta_mid
        const double b0  = shb[4 * lane],     b1  = shb[4 * lane + 1];
        const double b2  = shb[4 * lane + 2], b3  = shb[4 * lane + 3];
        const double b4r = shb[4 * lane + 4]; // lane63 -> shb[256]
        const double b5r = shb[4 * lane + 5]; // lane63 -> shb[257] = 0
        const double g0 = b0 + b1;
        const double g1 = fma(sk3d, b3, b1 + b2);
        const double g2 = b2 + b3;
        const double g3 = fma(skBd, b5r, b3 + b4r);
        double c = a0 * g0 + a1 * g1 + a2 * g2 + a3 * g3;
        if (lane == 63) c += a4 * shb[256];   // succ(256) = {256}
#pragma unroll
        for (int off = 32; off; off >>= 1) c += __shfl_xor(c, off);
        if (lane == 0) {
            const double loss = (double)ssw -
                (log(c) + (double)(shk[0] + shk[1]) * 0.6931471805599453);
            atomicAdd(out, (float)(loss * (1.0 / (double)BB)));
        }
    }
}

extern "C" void kernel_launch(void* const* d_in, const int* in_sizes, int n_in,
                              void* d_out, int out_size, void* d_ws, size_t ws_size,
                              hipStream_t stream) {
    const float* ys_hat  = (const float*)d_in[0];
    const int*   ys_pad  = (const int*)d_in[1];
    const int*   hlens   = (const int*)d_in[2];
    const int*   ys_lens = (const int*)d_in[3];
    float* out = (float*)d_out;

    float* lp_raw = (float*)d_ws;        // [B, T, SP] floats (~35.7 MB)

    // out is zeroed by ctc_row_kernel block 0 (stream-ordered before dp).
    ctc_row_kernel<<<BB * TT / (4 * RPW), 256, 0, stream>>>(ys_hat, ys_pad, hlens, lp_raw, out);
    ctc_dp_kernel<<<BB, 128, 0, stream>>>(lp_raw, ys_pad, hlens, ys_lens, out);
}